// Round 1
// baseline (762.977 us; speedup 1.0000x reference)
//
#include <hip/hip_runtime.h>
#include <math.h>

// Problem constants (fixed by reference)
#define BB  2
#define SS  2048
#define DD  768
#define HH  12
#define HDD 64
#define BSR (BB * SS)   // 4096 rows

// ---------------------------------------------------------------------------
// Kernel 1: QKV projection.  out = x @ W + b for W in {wq,wk,wv}, written to
// q/k/v in [B][H][S][HD] layout.  64x64 tile, BK=16, 256 thr, 4x4 per thread.
// ---------------------------------------------------------------------------
__global__ __launch_bounds__(256) void qkv_proj_kernel(
    const float* __restrict__ x,
    const float* __restrict__ wq, const float* __restrict__ bq,
    const float* __restrict__ wk, const float* __restrict__ bk,
    const float* __restrict__ wv, const float* __restrict__ bv,
    float* __restrict__ qo, float* __restrict__ ko, float* __restrict__ vo)
{
    const int which = blockIdx.z;
    const float* w    = (which == 0) ? wq : (which == 1) ? wk : wv;
    const float* bias = (which == 0) ? bq : (which == 1) ? bk : bv;
    float* out        = (which == 0) ? qo : (which == 1) ? ko : vo;

    const int row0 = blockIdx.x * 64;   // over BSR
    const int col0 = blockIdx.y * 64;   // over DD (one head per tile: HD==64)
    const int tid  = threadIdx.x;
    const int tx   = tid & 15;
    const int ty   = tid >> 4;

    // As padded to 68 to break the 4-way transpose-store conflict; Bs stores
    // are row-contiguous float4 (conflict-free unpadded) and reads are 2-way
    // (free per m136).
    __shared__ float As[16][68];   // As[k][m]
    __shared__ float Bs[16][64];   // Bs[k][n]

    float acc[4][4];
#pragma unroll
    for (int i = 0; i < 4; ++i)
#pragma unroll
        for (int j = 0; j < 4; ++j) acc[i][j] = 0.f;

    const int ar = tid >> 2;         // 0..63: A-tile row
    const int ac = (tid & 3) * 4;    // k-chunk within tile
    const int br = tid >> 4;         // 0..15: B-tile k-row
    const int bc = (tid & 15) * 4;   // B-tile col chunk

    for (int k0 = 0; k0 < DD; k0 += 16) {
        float4 av  = *(const float4*)&x[(size_t)(row0 + ar) * DD + k0 + ac];
        float4 bv4 = *(const float4*)&w[(size_t)(k0 + br) * DD + col0 + bc];
        As[ac + 0][ar] = av.x;
        As[ac + 1][ar] = av.y;
        As[ac + 2][ar] = av.z;
        As[ac + 3][ar] = av.w;
        *(float4*)&Bs[br][bc] = bv4;
        __syncthreads();
#pragma unroll
        for (int kk = 0; kk < 16; ++kk) {
            float4 a = *(const float4*)&As[kk][ty * 4];
            float4 b = *(const float4*)&Bs[kk][tx * 4];
            float ai[4] = {a.x, a.y, a.z, a.w};
            float bj[4] = {b.x, b.y, b.z, b.w};
#pragma unroll
            for (int i = 0; i < 4; ++i)
#pragma unroll
                for (int j = 0; j < 4; ++j)
                    acc[i][j] = fmaf(ai[i], bj[j], acc[i][j]);
        }
        __syncthreads();
    }

    const int h = blockIdx.y;                 // head index (HD==64 tile)
    float4 bias4 = *(const float4*)&bias[col0 + tx * 4];
    float bj[4] = {bias4.x, bias4.y, bias4.z, bias4.w};
#pragma unroll
    for (int i = 0; i < 4; ++i) {
        int m = row0 + ty * 4 + i;
        int b = m >> 11;           // / 2048
        int s = m & 2047;
        float4 o;
        o.x = acc[i][0] + bj[0];
        o.y = acc[i][1] + bj[1];
        o.z = acc[i][2] + bj[2];
        o.w = acc[i][3] + bj[3];
        *(float4*)&out[(((size_t)(b * HH + h)) * SS + s) * HDD + tx * 4] = o;
    }
}

// ---------------------------------------------------------------------------
// Kernel 2: causal flash attention over one (b, h, 64-row Q tile) per block.
// Online softmax; GEMM-pattern LDS reads (broadcast / 2-way => conflict-free).
// LDS = 4 * 64*64*4B = 64 KiB exactly -> 2 blocks/CU.
// ---------------------------------------------------------------------------
__global__ __launch_bounds__(256) void attn_kernel(
    const float* __restrict__ q, const float* __restrict__ k,
    const float* __restrict__ v, float* __restrict__ ctx)
{
    const int qt = blockIdx.x;   // 0..31
    const int h  = blockIdx.y;
    const int b  = blockIdx.z;
    const size_t base = ((size_t)(b * HH + h)) * SS * HDD;
    const float* qp = q + base;
    const float* kp = k + base;
    const float* vp = v + base;

    const int tid = threadIdx.x;
    const int tx  = tid & 15;
    const int ty  = tid >> 4;
    const int q0  = qt * 64;

    __shared__ float Qs[64][64];   // Qs[d][r]   (Q transposed)
    __shared__ float Ks[64][64];   // Ks[d][ki]  (K transposed)
    __shared__ float Vs[64][64];   // Vs[ki][d]  (natural)
    __shared__ float Ps[64][64];   // Ps[ki][r]  (P transposed)

    // Load Q tile transposed (once per block).
    {
        const int r  = tid >> 2;
        const int cg = (tid & 3) * 16;
#pragma unroll
        for (int q4 = 0; q4 < 4; ++q4) {
            float4 t = *(const float4*)&qp[(size_t)(q0 + r) * HDD + cg + q4 * 4];
            Qs[cg + q4 * 4 + 0][r] = t.x;
            Qs[cg + q4 * 4 + 1][r] = t.y;
            Qs[cg + q4 * 4 + 2][r] = t.z;
            Qs[cg + q4 * 4 + 3][r] = t.w;
        }
    }

    float m_i[4], l_i[4], o[4][4];
#pragma unroll
    for (int i = 0; i < 4; ++i) {
        m_i[i] = -INFINITY;
        l_i[i] = 0.f;
#pragma unroll
        for (int j = 0; j < 4; ++j) o[i][j] = 0.f;
    }

    for (int kt = 0; kt <= qt; ++kt) {
        const int k0 = kt * 64;
        __syncthreads();   // prior PV reads of Ks/Vs/Ps complete
        {
            const int r  = tid >> 2;
            const int cg = (tid & 3) * 16;
#pragma unroll
            for (int q4 = 0; q4 < 4; ++q4) {
                float4 t = *(const float4*)&kp[(size_t)(k0 + r) * HDD + cg + q4 * 4];
                Ks[cg + q4 * 4 + 0][r] = t.x;
                Ks[cg + q4 * 4 + 1][r] = t.y;
                Ks[cg + q4 * 4 + 2][r] = t.z;
                Ks[cg + q4 * 4 + 3][r] = t.w;
                float4 tv = *(const float4*)&vp[(size_t)(k0 + r) * HDD + cg + q4 * 4];
                *(float4*)&Vs[r][cg + q4 * 4] = tv;
            }
        }
        __syncthreads();   // K/V (and Q on first iter) visible

        // scores s[i][j] = sum_d Q[q0+ty*4+i][d] * K[k0+tx*4+j][d]
        float s[4][4];
#pragma unroll
        for (int i = 0; i < 4; ++i)
#pragma unroll
            for (int j = 0; j < 4; ++j) s[i][j] = 0.f;

#pragma unroll 8
        for (int d = 0; d < 64; ++d) {
            float4 a = *(const float4*)&Qs[d][ty * 4];
            float4 c = *(const float4*)&Ks[d][tx * 4];
            float ai[4] = {a.x, a.y, a.z, a.w};
            float cj[4] = {c.x, c.y, c.z, c.w};
#pragma unroll
            for (int i = 0; i < 4; ++i)
#pragma unroll
                for (int j = 0; j < 4; ++j)
                    s[i][j] = fmaf(ai[i], cj[j], s[i][j]);
        }

        // scale + causal mask (diagonal tile only)
#pragma unroll
        for (int i = 0; i < 4; ++i)
#pragma unroll
            for (int j = 0; j < 4; ++j) {
                float val = s[i][j] * 0.125f;   // 1/sqrt(64)
                if (kt == qt) {
                    int qi = q0 + ty * 4 + i;
                    int kg = k0 + tx * 4 + j;
                    val = (kg > qi) ? -INFINITY : val;
                }
                s[i][j] = val;
            }

        // online softmax; each row's 64 scores live on 16 lanes (same ty)
        float p[4][4];
#pragma unroll
        for (int i = 0; i < 4; ++i) {
            float rmax = fmaxf(fmaxf(s[i][0], s[i][1]), fmaxf(s[i][2], s[i][3]));
#pragma unroll
            for (int off = 1; off < 16; off <<= 1)
                rmax = fmaxf(rmax, __shfl_xor(rmax, off, 64));
            float mn    = fmaxf(m_i[i], rmax);
            float scale = __expf(m_i[i] - mn);
            float rsum  = 0.f;
#pragma unroll
            for (int j = 0; j < 4; ++j) {
                p[i][j] = __expf(s[i][j] - mn);
                rsum += p[i][j];
            }
#pragma unroll
            for (int off = 1; off < 16; off <<= 1)
                rsum += __shfl_xor(rsum, off, 64);
            l_i[i] = l_i[i] * scale + rsum;
            m_i[i] = mn;
#pragma unroll
            for (int j = 0; j < 4; ++j) o[i][j] *= scale;
        }

        // stage P transposed for the PV GEMM
#pragma unroll
        for (int i = 0; i < 4; ++i)
#pragma unroll
            for (int j = 0; j < 4; ++j)
                Ps[tx * 4 + j][ty * 4 + i] = p[i][j];
        __syncthreads();   // Ps visible

        // O[i][j] += sum_ki P[r][ki] * V[ki][d],  r=ty*4+i, d=tx*4+j
#pragma unroll 8
        for (int ki = 0; ki < 64; ++ki) {
            float4 pa = *(const float4*)&Ps[ki][ty * 4];
            float4 vb = *(const float4*)&Vs[ki][tx * 4];
            float pi[4] = {pa.x, pa.y, pa.z, pa.w};
            float vj[4] = {vb.x, vb.y, vb.z, vb.w};
#pragma unroll
            for (int i = 0; i < 4; ++i)
#pragma unroll
                for (int j = 0; j < 4; ++j)
                    o[i][j] = fmaf(pi[i], vj[j], o[i][j]);
        }
    }

    // epilogue: divide by l, write ctx[b*S+s][h*64 + d]
#pragma unroll
    for (int i = 0; i < 4; ++i) {
        int   srow = q0 + ty * 4 + i;
        float inv  = 1.0f / l_i[i];
        float4 ov;
        ov.x = o[i][0] * inv;
        ov.y = o[i][1] * inv;
        ov.z = o[i][2] * inv;
        ov.w = o[i][3] * inv;
        *(float4*)&ctx[((size_t)(b * SS + srow)) * DD + h * HDD + tx * 4] = ov;
    }
}

// ---------------------------------------------------------------------------
// Kernel 3: output projection out = ctx @ wo + bo  ([BSR][DD] row-major out).
// ---------------------------------------------------------------------------
__global__ __launch_bounds__(256) void out_proj_kernel(
    const float* __restrict__ ctx, const float* __restrict__ wo,
    const float* __restrict__ bo, float* __restrict__ out)
{
    const int row0 = blockIdx.x * 64;
    const int col0 = blockIdx.y * 64;
    const int tid  = threadIdx.x;
    const int tx   = tid & 15;
    const int ty   = tid >> 4;

    __shared__ float As[16][68];
    __shared__ float Bs[16][64];

    float acc[4][4];
#pragma unroll
    for (int i = 0; i < 4; ++i)
#pragma unroll
        for (int j = 0; j < 4; ++j) acc[i][j] = 0.f;

    const int ar = tid >> 2;
    const int ac = (tid & 3) * 4;
    const int br = tid >> 4;
    const int bc = (tid & 15) * 4;

    for (int k0 = 0; k0 < DD; k0 += 16) {
        float4 av  = *(const float4*)&ctx[(size_t)(row0 + ar) * DD + k0 + ac];
        float4 bv4 = *(const float4*)&wo[(size_t)(k0 + br) * DD + col0 + bc];
        As[ac + 0][ar] = av.x;
        As[ac + 1][ar] = av.y;
        As[ac + 2][ar] = av.z;
        As[ac + 3][ar] = av.w;
        *(float4*)&Bs[br][bc] = bv4;
        __syncthreads();
#pragma unroll
        for (int kk = 0; kk < 16; ++kk) {
            float4 a = *(const float4*)&As[kk][ty * 4];
            float4 b = *(const float4*)&Bs[kk][tx * 4];
            float ai[4] = {a.x, a.y, a.z, a.w};
            float bj[4] = {b.x, b.y, b.z, b.w};
#pragma unroll
            for (int i = 0; i < 4; ++i)
#pragma unroll
                for (int j = 0; j < 4; ++j)
                    acc[i][j] = fmaf(ai[i], bj[j], acc[i][j]);
        }
        __syncthreads();
    }

    float4 bias4 = *(const float4*)&bo[col0 + tx * 4];
    float bj[4] = {bias4.x, bias4.y, bias4.z, bias4.w};
#pragma unroll
    for (int i = 0; i < 4; ++i) {
        int m = row0 + ty * 4 + i;
        float4 o;
        o.x = acc[i][0] + bj[0];
        o.y = acc[i][1] + bj[1];
        o.z = acc[i][2] + bj[2];
        o.w = acc[i][3] + bj[3];
        *(float4*)&out[(size_t)m * DD + col0 + tx * 4] = o;
    }
}

// ---------------------------------------------------------------------------
extern "C" void kernel_launch(void* const* d_in, const int* in_sizes, int n_in,
                              void* d_out, int out_size, void* d_ws, size_t ws_size,
                              hipStream_t stream)
{
    const float* x  = (const float*)d_in[0];
    const float* wq = (const float*)d_in[1];
    const float* bq = (const float*)d_in[2];
    const float* wk = (const float*)d_in[3];
    const float* bk = (const float*)d_in[4];
    const float* wv = (const float*)d_in[5];
    const float* bv = (const float*)d_in[6];
    const float* wo = (const float*)d_in[7];
    const float* bo = (const float*)d_in[8];
    float* out = (float*)d_out;

    float* ws = (float*)d_ws;
    const size_t per = (size_t)BB * HH * SS * HDD;   // 3,145,728 floats each
    float* qb = ws;
    float* kb = ws + per;
    float* vb = ws + 2 * per;
    float* cb = ws + 3 * per;                        // ctx, [BSR][DD]

    qkv_proj_kernel<<<dim3(BSR / 64, DD / 64, 3), 256, 0, stream>>>(
        x, wq, bq, wk, bk, wv, bv, qb, kb, vb);
    attn_kernel<<<dim3(SS / 64, HH, BB), 256, 0, stream>>>(qb, kb, vb, cb);
    out_proj_kernel<<<dim3(BSR / 64, DD / 64), 256, 0, stream>>>(cb, wo, bo, out);
}

// Round 2
// 249.895 us; speedup vs baseline: 3.0532x; 3.0532x over previous
//
#include <hip/hip_runtime.h>
#include <math.h>

#define BB  2
#define SS  2048
#define DD  768
#define HH  12
#define HDD 64
#define BSR (BB * SS)   // 4096

typedef __attribute__((ext_vector_type(8))) short bf16x8;   // 8 bf16 = 4 VGPRs
typedef __attribute__((ext_vector_type(4))) float f32x4;
typedef __attribute__((ext_vector_type(4))) int  i32x4;     // 16B copy unit

__device__ inline f32x4 mfma16(bf16x8 a, bf16x8 b, f32x4 c) {
    return __builtin_amdgcn_mfma_f32_16x16x32_bf16(a, b, c, 0, 0, 0);
}

// fp32 -> bf16 with round-to-nearest-even (manual, type-agnostic)
__device__ inline unsigned short f2b(float f) {
    unsigned int u = __float_as_uint(f);
    u += 0x7FFFu + ((u >> 16) & 1u);
    return (unsigned short)(u >> 16);
}

// ---------------------------------------------------------------------------
// Conversion kernels
// ---------------------------------------------------------------------------
__global__ __launch_bounds__(256) void conv_x_kernel(
    const float* __restrict__ x, unsigned short* __restrict__ xb)
{
    int id = blockIdx.x * 256 + threadIdx.x;     // 8 elements per thread
    size_t base = (size_t)id * 8;
    float4 a = *(const float4*)&x[base];
    float4 b = *(const float4*)&x[base + 4];
    unsigned short o[8] = {f2b(a.x), f2b(a.y), f2b(a.z), f2b(a.w),
                           f2b(b.x), f2b(b.y), f2b(b.z), f2b(b.w)};
    *(i32x4*)&xb[base] = *(const i32x4*)o;
}

// transpose-convert: w[k][n] fp32 -> wT[n][k] bf16, 64x64 LDS tiles
__global__ __launch_bounds__(256) void conv_wT_kernel(
    const float* __restrict__ w0, const float* __restrict__ w1,
    const float* __restrict__ w2, const float* __restrict__ w3,
    unsigned short* __restrict__ o0, unsigned short* __restrict__ o1,
    unsigned short* __restrict__ o2, unsigned short* __restrict__ o3)
{
    const float* w = (blockIdx.z == 0) ? w0 : (blockIdx.z == 1) ? w1
                   : (blockIdx.z == 2) ? w2 : w3;
    unsigned short* o = (blockIdx.z == 0) ? o0 : (blockIdx.z == 1) ? o1
                      : (blockIdx.z == 2) ? o2 : o3;
    const int n0 = blockIdx.x * 64;
    const int k0 = blockIdx.y * 64;
    const int tid = threadIdx.x;

    __shared__ unsigned short tile[64][72];   // [n][k], padded

    // load 64 k-rows x 64 n-cols, 16 float4 per row -> 1024 chunks, 4/thread
#pragma unroll
    for (int p = 0; p < 4; ++p) {
        int c  = p * 256 + tid;
        int kr = c >> 4;
        int nc = (c & 15) * 4;
        float4 v = *(const float4*)&w[(size_t)(k0 + kr) * DD + n0 + nc];
        tile[nc + 0][kr] = f2b(v.x);
        tile[nc + 1][kr] = f2b(v.y);
        tile[nc + 2][kr] = f2b(v.z);
        tile[nc + 3][kr] = f2b(v.w);
    }
    __syncthreads();
    // store 64 n-rows x 64 k bf16 = 8 chunks/row -> 512 chunks, 2/thread
#pragma unroll
    for (int p = 0; p < 2; ++p) {
        int c  = p * 256 + tid;
        int nr = c >> 3;
        int kc = (c & 7) * 8;
        *(i32x4*)&o[(size_t)(n0 + nr) * DD + k0 + kc] = *(const i32x4*)&tile[nr][kc];
    }
}

// ---------------------------------------------------------------------------
// Shared MFMA GEMM main loop: C[128x128] = A[128xK] * Bt[128xK]^T (bf16)
// block 256 thr = 4 waves, wave quadrant (mh,nh), 16 mfma / BK=32 iter.
// ---------------------------------------------------------------------------
__device__ inline void gemm_mainloop(
    const unsigned short* __restrict__ A, const unsigned short* __restrict__ Bt,
    unsigned short (*As)[32], unsigned short (*Bs)[32],
    f32x4 acc[4][4], int m0, int n0, int tid, int mh, int nh, int l16, int quad)
{
    for (int k0 = 0; k0 < DD; k0 += 32) {
        __syncthreads();
#pragma unroll
        for (int p = 0; p < 2; ++p) {
            int c = p * 256 + tid;
            int r = c >> 2;
            int o = (c & 3) * 8;
            *(i32x4*)&As[r][o] = *(const i32x4*)&A[(size_t)(m0 + r) * DD + k0 + o];
            *(i32x4*)&Bs[r][o] = *(const i32x4*)&Bt[(size_t)(n0 + r) * DD + k0 + o];
        }
        __syncthreads();
        bf16x8 af[4], bf[4];
#pragma unroll
        for (int mt = 0; mt < 4; ++mt)
            af[mt] = *(const bf16x8*)&As[mh * 64 + mt * 16 + l16][quad * 8];
#pragma unroll
        for (int nt = 0; nt < 4; ++nt)
            bf[nt] = *(const bf16x8*)&Bs[nh * 64 + nt * 16 + l16][quad * 8];
#pragma unroll
        for (int mt = 0; mt < 4; ++mt)
#pragma unroll
            for (int nt = 0; nt < 4; ++nt)
                acc[mt][nt] = mfma16(af[mt], bf[nt], acc[mt][nt]);
    }
}

// ---------------------------------------------------------------------------
// QKV projection GEMM: z selects {Q,K,V}.  Q,K -> natural bf16 [bh][s][64];
// V -> transposed bf16 [bh][d][s].
// ---------------------------------------------------------------------------
__global__ __launch_bounds__(256) void qkv_gemm_kernel(
    const unsigned short* __restrict__ xb,
    const unsigned short* __restrict__ wqT, const unsigned short* __restrict__ wkT,
    const unsigned short* __restrict__ wvT,
    const float* __restrict__ bq, const float* __restrict__ bk,
    const float* __restrict__ bv,
    unsigned short* __restrict__ Qg, unsigned short* __restrict__ Kg,
    unsigned short* __restrict__ Vg)
{
    const int which = blockIdx.z;
    const unsigned short* Bt = (which == 0) ? wqT : (which == 1) ? wkT : wvT;
    const float* bias        = (which == 0) ? bq  : (which == 1) ? bk  : bv;
    unsigned short* out      = (which == 0) ? Qg  : (which == 1) ? Kg  : Vg;

    const int m0 = blockIdx.x * 128;
    const int n0 = blockIdx.y * 128;
    const int tid  = threadIdx.x;
    const int w    = tid >> 6;
    const int lane = tid & 63;
    const int quad = lane >> 4;
    const int l16  = lane & 15;
    const int mh   = w & 1;
    const int nh   = w >> 1;

    __shared__ unsigned short As[128][32];
    __shared__ unsigned short Bs[128][32];

    f32x4 zero = {0.f, 0.f, 0.f, 0.f};
    f32x4 acc[4][4];
#pragma unroll
    for (int i = 0; i < 4; ++i)
#pragma unroll
        for (int j = 0; j < 4; ++j) acc[i][j] = zero;

    gemm_mainloop(xb, Bt, As, Bs, acc, m0, n0, tid, mh, nh, l16, quad);

    const int nbase = n0 + nh * 64;       // 64-aligned -> exactly one head
    const int hcol  = nbase >> 6;
#pragma unroll
    for (int nt = 0; nt < 4; ++nt) {
        const int d  = nt * 16 + l16;
        const float bvv = bias[nbase + d];
#pragma unroll
        for (int mt = 0; mt < 4; ++mt) {
            const int mbase = m0 + mh * 64 + mt * 16 + quad * 4;
            const int b  = mbase >> 11;
            const int s  = mbase & 2047;
            if (which < 2) {
#pragma unroll
                for (int r = 0; r < 4; ++r)
                    out[(((size_t)(b * HH + hcol)) * SS + s + r) * HDD + d] =
                        f2b(acc[mt][nt][r] + bvv);
            } else {
                ushort4 pk;
                pk.x = f2b(acc[mt][nt][0] + bvv);
                pk.y = f2b(acc[mt][nt][1] + bvv);
                pk.z = f2b(acc[mt][nt][2] + bvv);
                pk.w = f2b(acc[mt][nt][3] + bvv);
                *(ushort4*)&out[(((size_t)(b * HH + hcol)) * HDD + d) * SS + s] = pk;
            }
        }
    }
}

// ---------------------------------------------------------------------------
// Output projection GEMM: ctx(bf16) @ woT + bo -> fp32 out
// ---------------------------------------------------------------------------
__global__ __launch_bounds__(256) void out_gemm_kernel(
    const unsigned short* __restrict__ cb, const unsigned short* __restrict__ woT,
    const float* __restrict__ bo, float* __restrict__ out)
{
    const int m0 = blockIdx.x * 128;
    const int n0 = blockIdx.y * 128;
    const int tid  = threadIdx.x;
    const int w    = tid >> 6;
    const int lane = tid & 63;
    const int quad = lane >> 4;
    const int l16  = lane & 15;
    const int mh   = w & 1;
    const int nh   = w >> 1;

    __shared__ unsigned short As[128][32];
    __shared__ unsigned short Bs[128][32];

    f32x4 zero = {0.f, 0.f, 0.f, 0.f};
    f32x4 acc[4][4];
#pragma unroll
    for (int i = 0; i < 4; ++i)
#pragma unroll
        for (int j = 0; j < 4; ++j) acc[i][j] = zero;

    gemm_mainloop(cb, woT, As, Bs, acc, m0, n0, tid, mh, nh, l16, quad);

#pragma unroll
    for (int nt = 0; nt < 4; ++nt) {
        const int n = n0 + nh * 64 + nt * 16 + l16;
        const float bvv = bo[n];
#pragma unroll
        for (int mt = 0; mt < 4; ++mt) {
            const int mbase = m0 + mh * 64 + mt * 16 + quad * 4;
#pragma unroll
            for (int r = 0; r < 4; ++r)
                out[(size_t)(mbase + r) * DD + n] = acc[mt][nt][r] + bvv;
        }
    }
}

// ---------------------------------------------------------------------------
// MFMA flash attention.  Block = (qt, h, b), 4 waves, wave = 16 Q rows.
// Q/K natural bf16 [bh][s][64]; V transposed bf16 [bh][d][s].
// ---------------------------------------------------------------------------
__global__ __launch_bounds__(256) void attn_mfma_kernel(
    const unsigned short* __restrict__ Qg, const unsigned short* __restrict__ Kg,
    const unsigned short* __restrict__ Vg, unsigned short* __restrict__ ctx)
{
    const int qt = blockIdx.x;
    const int h  = blockIdx.y;
    const int b  = blockIdx.z;
    const int tid  = threadIdx.x;
    const int w    = tid >> 6;
    const int lane = tid & 63;
    const int quad = lane >> 4;
    const int l16  = lane & 15;
    const int q0   = qt * 64;

    const size_t bh = (size_t)(b * HH + h);
    const unsigned short* qp = Qg + bh * SS * HDD;
    const unsigned short* kp = Kg + bh * SS * HDD;
    const unsigned short* vp = Vg + bh * HDD * SS;   // [d][s]

    __shared__ unsigned short Qs[64][72];     // [q][d]
    __shared__ unsigned short Ks[64][72];     // [key][d]
    __shared__ unsigned short Vt[64][72];     // [d][key]
    __shared__ unsigned short Ps[4][16][72];  // per-wave P slab [m][key]

    // stage Q once: 64 rows x 128B = 512 x 16B chunks, 2/thread
#pragma unroll
    for (int p = 0; p < 2; ++p) {
        int c = p * 256 + tid;
        int r = c >> 3;
        int o = (c & 7) * 8;
        *(i32x4*)&Qs[r][o] = *(const i32x4*)&qp[(size_t)(q0 + r) * HDD + o];
    }

    f32x4 zero = {0.f, 0.f, 0.f, 0.f};
    f32x4 o_acc[4];
    float m_i[4], l_i[4];
#pragma unroll
    for (int i = 0; i < 4; ++i) { o_acc[i] = zero; m_i[i] = -INFINITY; l_i[i] = 0.f; }

    const int mrow = w * 16 + l16;   // a-frag row for QK

    for (int kt = 0; kt <= qt; ++kt) {
        const int k0 = kt * 64;
        __syncthreads();   // prior-iter reads done (also covers Q staging, iter 0)
#pragma unroll
        for (int p = 0; p < 2; ++p) {
            int c = p * 256 + tid;
            int r = c >> 3;
            int o = (c & 7) * 8;
            *(i32x4*)&Ks[r][o] = *(const i32x4*)&kp[(size_t)(k0 + r) * HDD + o];
            *(i32x4*)&Vt[r][o] = *(const i32x4*)&vp[(size_t)r * SS + k0 + o];
        }
        __syncthreads();

        // ---- S = Q K^T (16 x 64 per wave) ----
        f32x4 s_acc[4];
#pragma unroll
        for (int nt = 0; nt < 4; ++nt) s_acc[nt] = zero;
        bf16x8 a0 = *(const bf16x8*)&Qs[mrow][quad * 8];
        bf16x8 a1 = *(const bf16x8*)&Qs[mrow][32 + quad * 8];
#pragma unroll
        for (int nt = 0; nt < 4; ++nt) {
            bf16x8 b0 = *(const bf16x8*)&Ks[nt * 16 + l16][quad * 8];
            bf16x8 b1 = *(const bf16x8*)&Ks[nt * 16 + l16][32 + quad * 8];
            s_acc[nt] = mfma16(a0, b0, s_acc[nt]);
            s_acc[nt] = mfma16(a1, b1, s_acc[nt]);
        }

        // ---- online softmax in C-layout (col=l16, row=quad*4+reg) ----
#pragma unroll
        for (int r = 0; r < 4; ++r) {
            const int qrow = q0 + w * 16 + quad * 4 + r;
            float sv[4];
#pragma unroll
            for (int nt = 0; nt < 4; ++nt) {
                float val = s_acc[nt][r] * 0.125f;
                if (kt == qt && (k0 + nt * 16 + l16) > qrow) val = -INFINITY;
                sv[nt] = val;
            }
            float rmax = fmaxf(fmaxf(sv[0], sv[1]), fmaxf(sv[2], sv[3]));
#pragma unroll
            for (int off = 1; off < 16; off <<= 1)
                rmax = fmaxf(rmax, __shfl_xor(rmax, off));
            const float mnew  = fmaxf(m_i[r], rmax);
            const float alpha = __expf(m_i[r] - mnew);
            float rsum = 0.f;
#pragma unroll
            for (int nt = 0; nt < 4; ++nt) {
                float pv = __expf(sv[nt] - mnew);
                Ps[w][quad * 4 + r][nt * 16 + l16] = f2b(pv);
                rsum += pv;
            }
#pragma unroll
            for (int off = 1; off < 16; off <<= 1)
                rsum += __shfl_xor(rsum, off);
            l_i[r] = l_i[r] * alpha + rsum;
            m_i[r] = mnew;
#pragma unroll
            for (int nt = 0; nt < 4; ++nt) o_acc[nt][r] *= alpha;
        }

        // ---- O += P V  (P in A-layout from per-wave LDS; V rows from Vt) ----
        bf16x8 pa0 = *(const bf16x8*)&Ps[w][l16][quad * 8];
        bf16x8 pa1 = *(const bf16x8*)&Ps[w][l16][32 + quad * 8];
#pragma unroll
        for (int nt = 0; nt < 4; ++nt) {
            bf16x8 vb0 = *(const bf16x8*)&Vt[nt * 16 + l16][quad * 8];
            bf16x8 vb1 = *(const bf16x8*)&Vt[nt * 16 + l16][32 + quad * 8];
            o_acc[nt] = mfma16(pa0, vb0, o_acc[nt]);
            o_acc[nt] = mfma16(pa1, vb1, o_acc[nt]);
        }
    }

    // epilogue: ctx bf16 natural [b*S + q][h*64 + d]
    float inv[4];
#pragma unroll
    for (int r = 0; r < 4; ++r) inv[r] = 1.0f / l_i[r];
#pragma unroll
    for (int nt = 0; nt < 4; ++nt) {
#pragma unroll
        for (int r = 0; r < 4; ++r) {
            const int qrow = q0 + w * 16 + quad * 4 + r;
            ctx[((size_t)(b * SS + qrow)) * DD + h * HDD + nt * 16 + l16] =
                f2b(o_acc[nt][r] * inv[r]);
        }
    }
}

// ---------------------------------------------------------------------------
extern "C" void kernel_launch(void* const* d_in, const int* in_sizes, int n_in,
                              void* d_out, int out_size, void* d_ws, size_t ws_size,
                              hipStream_t stream)
{
    const float* x  = (const float*)d_in[0];
    const float* wq = (const float*)d_in[1];
    const float* bq = (const float*)d_in[2];
    const float* wk = (const float*)d_in[3];
    const float* bk = (const float*)d_in[4];
    const float* wv = (const float*)d_in[5];
    const float* bv = (const float*)d_in[6];
    const float* wo = (const float*)d_in[7];
    const float* bo = (const float*)d_in[8];
    float* out = (float*)d_out;

    char* p = (char*)d_ws;
    const size_t XB = (size_t)BSR * DD * 2;       // 6,291,456 B
    const size_t WB = (size_t)DD * DD * 2;        // 1,179,648 B
    unsigned short* xb  = (unsigned short*)p;            p += XB;
    unsigned short* wqT = (unsigned short*)p;            p += WB;
    unsigned short* wkT = (unsigned short*)p;            p += WB;
    unsigned short* wvT = (unsigned short*)p;            p += WB;
    unsigned short* woT = (unsigned short*)p;            p += WB;
    unsigned short* Qg  = (unsigned short*)p;            p += XB;
    unsigned short* Kg  = (unsigned short*)p;            p += XB;
    unsigned short* Vg  = (unsigned short*)p;            p += XB;
    unsigned short* cb  = (unsigned short*)p;            p += XB;

    conv_x_kernel<<<BSR * DD / (256 * 8), 256, 0, stream>>>(x, xb);
    conv_wT_kernel<<<dim3(DD / 64, DD / 64, 4), 256, 0, stream>>>(
        wq, wk, wv, wo, wqT, wkT, wvT, woT);
    qkv_gemm_kernel<<<dim3(BSR / 128, DD / 128, 3), 256, 0, stream>>>(
        xb, wqT, wkT, wvT, bq, bk, bv, Qg, Kg, Vg);
    attn_mfma_kernel<<<dim3(SS / 64, HH, BB), 256, 0, stream>>>(Qg, Kg, Vg, cb);
    out_gemm_kernel<<<dim3(BSR / 128, DD / 128), 256, 0, stream>>>(cb, woT, bo, out);
}

// Round 3
// 229.012 us; speedup vs baseline: 3.3316x; 1.0912x over previous
//
#include <hip/hip_runtime.h>
#include <math.h>

#define BB  2
#define SS  2048
#define DD  768
#define HH  12
#define HDD 64
#define BSR (BB * SS)   // 4096

typedef __attribute__((ext_vector_type(8))) short bf16x8;   // 8 bf16 = 4 VGPRs
typedef __attribute__((ext_vector_type(4))) float f32x4;
typedef __attribute__((ext_vector_type(4))) int  i32x4;     // 16B copy unit

__device__ inline f32x4 mfma16(bf16x8 a, bf16x8 b, f32x4 c) {
    return __builtin_amdgcn_mfma_f32_16x16x32_bf16(a, b, c, 0, 0, 0);
}

// fp32 -> bf16 round-to-nearest-even
__device__ inline unsigned short f2b(float f) {
    unsigned int u = __float_as_uint(f);
    u += 0x7FFFu + ((u >> 16) & 1u);
    return (unsigned short)(u >> 16);
}

// async global->LDS 16B copy (wave-uniform LDS base + lane*16 — layout must
// be lane-contiguous, which our unpadded 64B LDS rows satisfy)
__device__ inline void async_copy16(void* lds, const void* g) {
    __builtin_amdgcn_global_load_lds(
        (const __attribute__((address_space(1))) unsigned int*)g,
        (__attribute__((address_space(3))) unsigned int*)lds, 16, 0, 0);
}

// ---------------------------------------------------------------------------
// Conversion kernels
// ---------------------------------------------------------------------------
__global__ __launch_bounds__(256) void conv_x_kernel(
    const float* __restrict__ x, unsigned short* __restrict__ xb)
{
    int id = blockIdx.x * 256 + threadIdx.x;
    size_t base = (size_t)id * 8;
    float4 a = *(const float4*)&x[base];
    float4 b = *(const float4*)&x[base + 4];
    unsigned short o[8] = {f2b(a.x), f2b(a.y), f2b(a.z), f2b(a.w),
                           f2b(b.x), f2b(b.y), f2b(b.z), f2b(b.w)};
    *(i32x4*)&xb[base] = *(const i32x4*)o;
}

__global__ __launch_bounds__(256) void conv_wT_kernel(
    const float* __restrict__ w0, const float* __restrict__ w1,
    const float* __restrict__ w2, const float* __restrict__ w3,
    unsigned short* __restrict__ o0, unsigned short* __restrict__ o1,
    unsigned short* __restrict__ o2, unsigned short* __restrict__ o3)
{
    const float* w = (blockIdx.z == 0) ? w0 : (blockIdx.z == 1) ? w1
                   : (blockIdx.z == 2) ? w2 : w3;
    unsigned short* o = (blockIdx.z == 0) ? o0 : (blockIdx.z == 1) ? o1
                      : (blockIdx.z == 2) ? o2 : o3;
    const int n0 = blockIdx.x * 64;
    const int k0 = blockIdx.y * 64;
    const int tid = threadIdx.x;

    __shared__ unsigned short tile[64][72];

#pragma unroll
    for (int p = 0; p < 4; ++p) {
        int c  = p * 256 + tid;
        int kr = c >> 4;
        int nc = (c & 15) * 4;
        float4 v = *(const float4*)&w[(size_t)(k0 + kr) * DD + n0 + nc];
        tile[nc + 0][kr] = f2b(v.x);
        tile[nc + 1][kr] = f2b(v.y);
        tile[nc + 2][kr] = f2b(v.z);
        tile[nc + 3][kr] = f2b(v.w);
    }
    __syncthreads();
#pragma unroll
    for (int p = 0; p < 2; ++p) {
        int c  = p * 256 + tid;
        int nr = c >> 3;
        int kc = (c & 7) * 8;
        *(i32x4*)&o[(size_t)(n0 + nr) * DD + k0 + kc] = *(const i32x4*)&tile[nr][kc];
    }
}

// ---------------------------------------------------------------------------
// MFMA GEMM main loop (m97 staging): C[128x128] = A[128xK] * Bt[128xK]^T
// ---------------------------------------------------------------------------
__device__ inline void gemm_mainloop(
    const unsigned short* __restrict__ A, const unsigned short* __restrict__ Bt,
    unsigned short (*As)[32], unsigned short (*Bs)[32],
    f32x4 acc[4][4], int m0, int n0, int tid, int mh, int nh, int l16, int quad)
{
    const int r0 = tid >> 2;          // 0..63 (p adds 64)
    const int o  = (tid & 3) * 8;
    for (int k0 = 0; k0 < DD; k0 += 32) {
        __syncthreads();
#pragma unroll
        for (int p = 0; p < 2; ++p) {
            int rr = r0 + p * 64;
            async_copy16(&As[rr][o], &A[(size_t)(m0 + rr) * DD + k0 + o]);
            async_copy16(&Bs[rr][o], &Bt[(size_t)(n0 + rr) * DD + k0 + o]);
        }
        __syncthreads();
        bf16x8 af[4], bf[4];
#pragma unroll
        for (int mt = 0; mt < 4; ++mt)
            af[mt] = *(const bf16x8*)&As[mh * 64 + mt * 16 + l16][quad * 8];
#pragma unroll
        for (int nt = 0; nt < 4; ++nt)
            bf[nt] = *(const bf16x8*)&Bs[nh * 64 + nt * 16 + l16][quad * 8];
#pragma unroll
        for (int mt = 0; mt < 4; ++mt)
#pragma unroll
            for (int nt = 0; nt < 4; ++nt)
                acc[mt][nt] = mfma16(af[mt], bf[nt], acc[mt][nt]);
    }
}

// ---------------------------------------------------------------------------
// QKV projection GEMM: Q,K natural bf16 [bh][s][64]; V transposed [bh][d][s].
// ---------------------------------------------------------------------------
__global__ __launch_bounds__(256) void qkv_gemm_kernel(
    const unsigned short* __restrict__ xb,
    const unsigned short* __restrict__ wqT, const unsigned short* __restrict__ wkT,
    const unsigned short* __restrict__ wvT,
    const float* __restrict__ bq, const float* __restrict__ bk,
    const float* __restrict__ bv,
    unsigned short* __restrict__ Qg, unsigned short* __restrict__ Kg,
    unsigned short* __restrict__ Vg)
{
    const int which = blockIdx.z;
    const unsigned short* Bt = (which == 0) ? wqT : (which == 1) ? wkT : wvT;
    const float* bias        = (which == 0) ? bq  : (which == 1) ? bk  : bv;
    unsigned short* out      = (which == 0) ? Qg  : (which == 1) ? Kg  : Vg;

    const int m0 = blockIdx.x * 128;
    const int n0 = blockIdx.y * 128;
    const int tid  = threadIdx.x;
    const int w    = tid >> 6;
    const int lane = tid & 63;
    const int quad = lane >> 4;
    const int l16  = lane & 15;
    const int mh   = w & 1;
    const int nh   = w >> 1;

    __shared__ unsigned short As[128][32];
    __shared__ unsigned short Bs[128][32];

    f32x4 zero = {0.f, 0.f, 0.f, 0.f};
    f32x4 acc[4][4];
#pragma unroll
    for (int i = 0; i < 4; ++i)
#pragma unroll
        for (int j = 0; j < 4; ++j) acc[i][j] = zero;

    gemm_mainloop(xb, Bt, As, Bs, acc, m0, n0, tid, mh, nh, l16, quad);

    const int nbase = n0 + nh * 64;
    const int hcol  = nbase >> 6;
#pragma unroll
    for (int nt = 0; nt < 4; ++nt) {
        const int d  = nt * 16 + l16;
        const float bvv = bias[nbase + d];
#pragma unroll
        for (int mt = 0; mt < 4; ++mt) {
            const int mbase = m0 + mh * 64 + mt * 16 + quad * 4;
            const int b  = mbase >> 11;
            const int s  = mbase & 2047;
            if (which < 2) {
#pragma unroll
                for (int r = 0; r < 4; ++r)
                    out[(((size_t)(b * HH + hcol)) * SS + s + r) * HDD + d] =
                        f2b(acc[mt][nt][r] + bvv);
            } else {
                ushort4 pk;
                pk.x = f2b(acc[mt][nt][0] + bvv);
                pk.y = f2b(acc[mt][nt][1] + bvv);
                pk.z = f2b(acc[mt][nt][2] + bvv);
                pk.w = f2b(acc[mt][nt][3] + bvv);
                *(ushort4*)&out[(((size_t)(b * HH + hcol)) * HDD + d) * SS + s] = pk;
            }
        }
    }
}

// ---------------------------------------------------------------------------
// Output projection GEMM: ctx(bf16) @ woT + bo -> fp32 out
// ---------------------------------------------------------------------------
__global__ __launch_bounds__(256) void out_gemm_kernel(
    const unsigned short* __restrict__ cb, const unsigned short* __restrict__ woT,
    const float* __restrict__ bo, float* __restrict__ out)
{
    const int m0 = blockIdx.x * 128;
    const int n0 = blockIdx.y * 128;
    const int tid  = threadIdx.x;
    const int w    = tid >> 6;
    const int lane = tid & 63;
    const int quad = lane >> 4;
    const int l16  = lane & 15;
    const int mh   = w & 1;
    const int nh   = w >> 1;

    __shared__ unsigned short As[128][32];
    __shared__ unsigned short Bs[128][32];

    f32x4 zero = {0.f, 0.f, 0.f, 0.f};
    f32x4 acc[4][4];
#pragma unroll
    for (int i = 0; i < 4; ++i)
#pragma unroll
        for (int j = 0; j < 4; ++j) acc[i][j] = zero;

    gemm_mainloop(cb, woT, As, Bs, acc, m0, n0, tid, mh, nh, l16, quad);

#pragma unroll
    for (int nt = 0; nt < 4; ++nt) {
        const int n = n0 + nh * 64 + nt * 16 + l16;
        const float bvv = bo[n];
#pragma unroll
        for (int mt = 0; mt < 4; ++mt) {
            const int mbase = m0 + mh * 64 + mt * 16 + quad * 4;
#pragma unroll
            for (int r = 0; r < 4; ++r)
                out[(size_t)(mbase + r) * DD + n] = acc[mt][nt][r] + bvv;
        }
    }
}

// ---------------------------------------------------------------------------
// MFMA flash attention.  Block = (qt, h, b), 4 waves, wave = 16 Q rows.
// Q fragments in registers; K/V register-prefetched one tile ahead so the
// global load overlaps tile-t compute; biggest qt dispatched first.
// LDS 27.6 KiB -> 4 blocks/CU (launch_bounds cap).
// ---------------------------------------------------------------------------
__global__ __launch_bounds__(256, 4) void attn_mfma_kernel(
    const unsigned short* __restrict__ Qg, const unsigned short* __restrict__ Kg,
    const unsigned short* __restrict__ Vg, unsigned short* __restrict__ ctx)
{
    const int qt = (SS / 64 - 1) - blockIdx.x;   // big tiles first
    const int h  = blockIdx.y;
    const int b  = blockIdx.z;
    const int tid  = threadIdx.x;
    const int w    = tid >> 6;
    const int lane = tid & 63;
    const int quad = lane >> 4;
    const int l16  = lane & 15;
    const int q0   = qt * 64;

    const size_t bh = (size_t)(b * HH + h);
    const unsigned short* qp = Qg + bh * SS * HDD;
    const unsigned short* kp = Kg + bh * SS * HDD;
    const unsigned short* vp = Vg + bh * HDD * SS;   // [d][s]

    __shared__ unsigned short Ks[64][72];     // [key][d]
    __shared__ unsigned short Vt[64][72];     // [d][key]
    __shared__ unsigned short Ps[4][16][72];  // per-wave P slab [m][key]

    // Q fragments straight to registers (A-layout: row=l16-in-wave-tile,
    // k=quad*8+j), two K-halves
    const int mrow = q0 + w * 16 + l16;
    const bf16x8 qa0 = *(const bf16x8*)&qp[(size_t)mrow * HDD + quad * 8];
    const bf16x8 qa1 = *(const bf16x8*)&qp[(size_t)mrow * HDD + 32 + quad * 8];

    // K/V prefetch registers: 2 x 16B each per thread
    const int pr = tid >> 3;          // 0..31 (p adds 32)
    const int po = (tid & 7) * 8;
    i32x4 kpre[2], vpre[2];
#pragma unroll
    for (int p = 0; p < 2; ++p) {
        int r = pr + p * 32;
        kpre[p] = *(const i32x4*)&kp[(size_t)r * HDD + po];
        vpre[p] = *(const i32x4*)&vp[(size_t)r * SS + po];
    }

    f32x4 zero = {0.f, 0.f, 0.f, 0.f};
    f32x4 o_acc[4];
    float m_i[4], l_i[4];
#pragma unroll
    for (int i = 0; i < 4; ++i) { o_acc[i] = zero; m_i[i] = -INFINITY; l_i[i] = 0.f; }

    for (int kt = 0; kt <= qt; ++kt) {
        const int k0 = kt * 64;
        __syncthreads();   // prior-iter LDS reads complete
#pragma unroll
        for (int p = 0; p < 2; ++p) {
            int r = pr + p * 32;
            *(i32x4*)&Ks[r][po] = kpre[p];
            *(i32x4*)&Vt[r][po] = vpre[p];
        }
        __syncthreads();   // tile visible

        if (kt < qt) {
            const int kn = k0 + 64;
#pragma unroll
            for (int p = 0; p < 2; ++p) {
                int r = pr + p * 32;
                kpre[p] = *(const i32x4*)&kp[(size_t)(kn + r) * HDD + po];
                vpre[p] = *(const i32x4*)&vp[(size_t)r * SS + kn + po];
            }
        }

        // ---- S = Q K^T (16 x 64 per wave) ----
        f32x4 s_acc[4];
#pragma unroll
        for (int nt = 0; nt < 4; ++nt) s_acc[nt] = zero;
#pragma unroll
        for (int nt = 0; nt < 4; ++nt) {
            bf16x8 b0 = *(const bf16x8*)&Ks[nt * 16 + l16][quad * 8];
            bf16x8 b1 = *(const bf16x8*)&Ks[nt * 16 + l16][32 + quad * 8];
            s_acc[nt] = mfma16(qa0, b0, s_acc[nt]);
            s_acc[nt] = mfma16(qa1, b1, s_acc[nt]);
        }

        // ---- online softmax in C-layout (col=l16, row=quad*4+reg) ----
#pragma unroll
        for (int r = 0; r < 4; ++r) {
            const int qrow = q0 + w * 16 + quad * 4 + r;
            float sv[4];
#pragma unroll
            for (int nt = 0; nt < 4; ++nt) {
                float val = s_acc[nt][r] * 0.125f;
                if (kt == qt && (k0 + nt * 16 + l16) > qrow) val = -INFINITY;
                sv[nt] = val;
            }
            float rmax = fmaxf(fmaxf(sv[0], sv[1]), fmaxf(sv[2], sv[3]));
#pragma unroll
            for (int off = 1; off < 16; off <<= 1)
                rmax = fmaxf(rmax, __shfl_xor(rmax, off));
            const float mnew  = fmaxf(m_i[r], rmax);
            const float alpha = __expf(m_i[r] - mnew);
            float rsum = 0.f;
#pragma unroll
            for (int nt = 0; nt < 4; ++nt) {
                float pv = __expf(sv[nt] - mnew);
                Ps[w][quad * 4 + r][nt * 16 + l16] = f2b(pv);
                rsum += pv;
            }
#pragma unroll
            for (int off = 1; off < 16; off <<= 1)
                rsum += __shfl_xor(rsum, off);
            l_i[r] = l_i[r] * alpha + rsum;
            m_i[r] = mnew;
#pragma unroll
            for (int nt = 0; nt < 4; ++nt) o_acc[nt][r] *= alpha;
        }

        // ---- O += P V (P from per-wave LDS in A-layout; V rows from Vt) ----
        bf16x8 pa0 = *(const bf16x8*)&Ps[w][l16][quad * 8];
        bf16x8 pa1 = *(const bf16x8*)&Ps[w][l16][32 + quad * 8];
#pragma unroll
        for (int nt = 0; nt < 4; ++nt) {
            bf16x8 vb0 = *(const bf16x8*)&Vt[nt * 16 + l16][quad * 8];
            bf16x8 vb1 = *(const bf16x8*)&Vt[nt * 16 + l16][32 + quad * 8];
            o_acc[nt] = mfma16(pa0, vb0, o_acc[nt]);
            o_acc[nt] = mfma16(pa1, vb1, o_acc[nt]);
        }
    }

    // epilogue: ctx bf16 natural [b*S + q][h*64 + d]
    float inv[4];
#pragma unroll
    for (int r = 0; r < 4; ++r) inv[r] = 1.0f / l_i[r];
#pragma unroll
    for (int nt = 0; nt < 4; ++nt) {
#pragma unroll
        for (int r = 0; r < 4; ++r) {
            const int qrow = q0 + w * 16 + quad * 4 + r;
            ctx[((size_t)(b * SS + qrow)) * DD + h * HDD + nt * 16 + l16] =
                f2b(o_acc[nt][r] * inv[r]);
        }
    }
}

// ---------------------------------------------------------------------------
extern "C" void kernel_launch(void* const* d_in, const int* in_sizes, int n_in,
                              void* d_out, int out_size, void* d_ws, size_t ws_size,
                              hipStream_t stream)
{
    const float* x  = (const float*)d_in[0];
    const float* wq = (const float*)d_in[1];
    const float* bq = (const float*)d_in[2];
    const float* wk = (const float*)d_in[3];
    const float* bk = (const float*)d_in[4];
    const float* wv = (const float*)d_in[5];
    const float* bv = (const float*)d_in[6];
    const float* wo = (const float*)d_in[7];
    const float* bo = (const float*)d_in[8];
    float* out = (float*)d_out;

    char* p = (char*)d_ws;
    const size_t XB = (size_t)BSR * DD * 2;
    const size_t WB = (size_t)DD * DD * 2;
    unsigned short* xb  = (unsigned short*)p;            p += XB;
    unsigned short* wqT = (unsigned short*)p;            p += WB;
    unsigned short* wkT = (unsigned short*)p;            p += WB;
    unsigned short* wvT = (unsigned short*)p;            p += WB;
    unsigned short* woT = (unsigned short*)p;            p += WB;
    unsigned short* Qg  = (unsigned short*)p;            p += XB;
    unsigned short* Kg  = (unsigned short*)p;            p += XB;
    unsigned short* Vg  = (unsigned short*)p;            p += XB;
    unsigned short* cb  = (unsigned short*)p;            p += XB;

    conv_x_kernel<<<BSR * DD / (256 * 8), 256, 0, stream>>>(x, xb);
    conv_wT_kernel<<<dim3(DD / 64, DD / 64, 4), 256, 0, stream>>>(
        wq, wk, wv, wo, wqT, wkT, wvT, woT);
    qkv_gemm_kernel<<<dim3(BSR / 128, DD / 128, 3), 256, 0, stream>>>(
        xb, wqT, wkT, wvT, bq, bk, bv, Qg, Kg, Vg);
    attn_mfma_kernel<<<dim3(SS / 64, HH, BB), 256, 0, stream>>>(Qg, Kg, Vg, cb);
    out_gemm_kernel<<<dim3(BSR / 128, DD / 128), 256, 0, stream>>>(cb, woT, bo, out);
}

// Round 4
// 211.660 us; speedup vs baseline: 3.6047x; 1.0820x over previous
//
#include <hip/hip_runtime.h>
#include <math.h>

#define BB  2
#define SS  2048
#define DD  768
#define HH  12
#define HDD 64
#define BSR (BB * SS)   // 4096

typedef __attribute__((ext_vector_type(8))) short bf16x8;   // 8 bf16 = 4 VGPRs
typedef __attribute__((ext_vector_type(4))) float f32x4;
typedef __attribute__((ext_vector_type(4))) int  i32x4;     // 16B copy unit

__device__ inline f32x4 mfma16(bf16x8 a, bf16x8 b, f32x4 c) {
    return __builtin_amdgcn_mfma_f32_16x16x32_bf16(a, b, c, 0, 0, 0);
}

// fp32 -> bf16 round-to-nearest-even
__device__ inline unsigned short f2b(float f) {
    unsigned int u = __float_as_uint(f);
    u += 0x7FFFu + ((u >> 16) & 1u);
    return (unsigned short)(u >> 16);
}

// async global->LDS 16B copy (LDS dest must be wave-uniform base + lane*16)
__device__ inline void async_copy16(void* lds, const void* g) {
    __builtin_amdgcn_global_load_lds(
        (const __attribute__((address_space(1))) unsigned int*)g,
        (__attribute__((address_space(3))) unsigned int*)lds, 16, 0, 0);
}

// ---------------------------------------------------------------------------
// Conversion kernels
// ---------------------------------------------------------------------------
__global__ __launch_bounds__(256) void conv_x_kernel(
    const float* __restrict__ x, unsigned short* __restrict__ xb)
{
    int id = blockIdx.x * 256 + threadIdx.x;
    size_t base = (size_t)id * 8;
    float4 a = *(const float4*)&x[base];
    float4 b = *(const float4*)&x[base + 4];
    unsigned short o[8] = {f2b(a.x), f2b(a.y), f2b(a.z), f2b(a.w),
                           f2b(b.x), f2b(b.y), f2b(b.z), f2b(b.w)};
    *(i32x4*)&xb[base] = *(const i32x4*)o;
}

__global__ __launch_bounds__(256) void conv_wT_kernel(
    const float* __restrict__ w0, const float* __restrict__ w1,
    const float* __restrict__ w2, const float* __restrict__ w3,
    unsigned short* __restrict__ o0, unsigned short* __restrict__ o1,
    unsigned short* __restrict__ o2, unsigned short* __restrict__ o3)
{
    const float* w = (blockIdx.z == 0) ? w0 : (blockIdx.z == 1) ? w1
                   : (blockIdx.z == 2) ? w2 : w3;
    unsigned short* o = (blockIdx.z == 0) ? o0 : (blockIdx.z == 1) ? o1
                      : (blockIdx.z == 2) ? o2 : o3;
    const int n0 = blockIdx.x * 64;
    const int k0 = blockIdx.y * 64;
    const int tid = threadIdx.x;

    __shared__ unsigned short tile[64][72];

#pragma unroll
    for (int p = 0; p < 4; ++p) {
        int c  = p * 256 + tid;
        int kr = c >> 4;
        int nc = (c & 15) * 4;
        float4 v = *(const float4*)&w[(size_t)(k0 + kr) * DD + n0 + nc];
        tile[nc + 0][kr] = f2b(v.x);
        tile[nc + 1][kr] = f2b(v.y);
        tile[nc + 2][kr] = f2b(v.z);
        tile[nc + 3][kr] = f2b(v.w);
    }
    __syncthreads();
#pragma unroll
    for (int p = 0; p < 2; ++p) {
        int c  = p * 256 + tid;
        int nr = c >> 3;
        int kc = (c & 7) * 8;
        *(i32x4*)&o[(size_t)(n0 + nr) * DD + k0 + kc] = *(const i32x4*)&tile[nr][kc];
    }
}

// ---------------------------------------------------------------------------
// MFMA GEMM main loop (m97 staging): C[128x128] = A[128xK] * Bt[128xK]^T
// ---------------------------------------------------------------------------
__device__ inline void gemm_mainloop(
    const unsigned short* __restrict__ A, const unsigned short* __restrict__ Bt,
    unsigned short (*As)[32], unsigned short (*Bs)[32],
    f32x4 acc[4][4], int m0, int n0, int tid, int mh, int nh, int l16, int quad)
{
    const int r0 = tid >> 2;
    const int o  = (tid & 3) * 8;
    for (int k0 = 0; k0 < DD; k0 += 32) {
        __syncthreads();
#pragma unroll
        for (int p = 0; p < 2; ++p) {
            int rr = r0 + p * 64;
            async_copy16(&As[rr][o], &A[(size_t)(m0 + rr) * DD + k0 + o]);
            async_copy16(&Bs[rr][o], &Bt[(size_t)(n0 + rr) * DD + k0 + o]);
        }
        __syncthreads();
        bf16x8 af[4], bf[4];
#pragma unroll
        for (int mt = 0; mt < 4; ++mt)
            af[mt] = *(const bf16x8*)&As[mh * 64 + mt * 16 + l16][quad * 8];
#pragma unroll
        for (int nt = 0; nt < 4; ++nt)
            bf[nt] = *(const bf16x8*)&Bs[nh * 64 + nt * 16 + l16][quad * 8];
#pragma unroll
        for (int mt = 0; mt < 4; ++mt)
#pragma unroll
            for (int nt = 0; nt < 4; ++nt)
                acc[mt][nt] = mfma16(af[mt], bf[nt], acc[mt][nt]);
    }
}

// ---------------------------------------------------------------------------
// QKV projection GEMM.  Q,K -> natural bf16 [bh][s][64]; V -> [bh][d][s].
// Epilogue re-layouts through LDS for fully coalesced 16B stores.
// ---------------------------------------------------------------------------
__global__ __launch_bounds__(256) void qkv_gemm_kernel(
    const unsigned short* __restrict__ xb,
    const unsigned short* __restrict__ wqT, const unsigned short* __restrict__ wkT,
    const unsigned short* __restrict__ wvT,
    const float* __restrict__ bq, const float* __restrict__ bk,
    const float* __restrict__ bv,
    unsigned short* __restrict__ Qg, unsigned short* __restrict__ Kg,
    unsigned short* __restrict__ Vg)
{
    const int which = blockIdx.z;
    const unsigned short* Bt = (which == 0) ? wqT : (which == 1) ? wkT : wvT;
    const float* bias        = (which == 0) ? bq  : (which == 1) ? bk  : bv;
    unsigned short* out      = (which == 0) ? Qg  : (which == 1) ? Kg  : Vg;

    const int m0 = blockIdx.x * 128;
    const int n0 = blockIdx.y * 128;
    const int tid  = threadIdx.x;
    const int w    = tid >> 6;
    const int lane = tid & 63;
    const int quad = lane >> 4;
    const int l16  = lane & 15;
    const int mh   = w & 1;
    const int nh   = w >> 1;

    // union: staging (As 4096 + Bs 4096 shorts) vs epilogue T[64][136] (8704)
    __shared__ unsigned short smem[8704];
    unsigned short (*As)[32] = (unsigned short(*)[32])smem;
    unsigned short (*Bs)[32] = (unsigned short(*)[32])(smem + 4096);
    unsigned short (*T)[136] = (unsigned short(*)[136])smem;

    f32x4 zero = {0.f, 0.f, 0.f, 0.f};
    f32x4 acc[4][4];
#pragma unroll
    for (int i = 0; i < 4; ++i)
#pragma unroll
        for (int j = 0; j < 4; ++j) acc[i][j] = zero;

    gemm_mainloop(xb, Bt, As, Bs, acc, m0, n0, tid, mh, nh, l16, quad);

    __syncthreads();   // staging reads done before T overwrite

    for (int pass = 0; pass < 2; ++pass) {
        if (pass) __syncthreads();   // pass-0 stores done before overwrite
        if (which < 2) {
            // Q/K: T[s_local][d 0..127], pass = s-half (mh)
            if (mh == pass) {
#pragma unroll
                for (int nt = 0; nt < 4; ++nt) {
                    const int n = n0 + nh * 64 + nt * 16 + l16;
                    const float bvv = bias[n];
#pragma unroll
                    for (int mt = 0; mt < 4; ++mt)
#pragma unroll
                        for (int r = 0; r < 4; ++r)
                            T[mt * 16 + quad * 4 + r][nh * 64 + nt * 16 + l16] =
                                f2b(acc[mt][nt][r] + bvv);
                }
            }
            __syncthreads();
#pragma unroll
            for (int p2 = 0; p2 < 4; ++p2) {
                int c    = p2 * 256 + tid;
                int row  = c >> 4;
                int ck   = c & 15;
                int head = ck >> 3;
                int wi   = ck & 7;
                int sg   = m0 + pass * 64 + row;
                int bi   = sg >> 11, si = sg & 2047;
                int hcol = (n0 >> 6) + head;
                *(i32x4*)&out[(((size_t)(bi * HH + hcol)) * SS + si) * HDD + wi * 8] =
                    *(const i32x4*)&T[row][head * 64 + wi * 8];
            }
        } else {
            // V: T[d_local][s 0..127] (transpose), pass = head (nh)
            if (nh == pass) {
#pragma unroll
                for (int nt = 0; nt < 4; ++nt) {
                    const int n = n0 + pass * 64 + nt * 16 + l16;
                    const float bvv = bias[n];
#pragma unroll
                    for (int mt = 0; mt < 4; ++mt) {
                        ushort4 pk;
                        pk.x = f2b(acc[mt][nt][0] + bvv);
                        pk.y = f2b(acc[mt][nt][1] + bvv);
                        pk.z = f2b(acc[mt][nt][2] + bvv);
                        pk.w = f2b(acc[mt][nt][3] + bvv);
                        *(ushort4*)&T[nt * 16 + l16][mh * 64 + mt * 16 + quad * 4] = pk;
                    }
                }
            }
            __syncthreads();
            const int bi   = m0 >> 11;
            const int s0   = m0 & 2047;
            const int hcol = (n0 >> 6) + pass;
#pragma unroll
            for (int p2 = 0; p2 < 4; ++p2) {
                int c    = p2 * 256 + tid;
                int drow = c >> 4;
                int wi   = c & 15;
                *(i32x4*)&out[(((size_t)(bi * HH + hcol)) * HDD + drow) * SS + s0 + wi * 8] =
                    *(const i32x4*)&T[drow][wi * 8];
            }
        }
    }
}

// ---------------------------------------------------------------------------
// Output projection GEMM: ctx(bf16) @ woT + bo -> fp32 out
// ---------------------------------------------------------------------------
__global__ __launch_bounds__(256) void out_gemm_kernel(
    const unsigned short* __restrict__ cb, const unsigned short* __restrict__ woT,
    const float* __restrict__ bo, float* __restrict__ out)
{
    const int m0 = blockIdx.x * 128;
    const int n0 = blockIdx.y * 128;
    const int tid  = threadIdx.x;
    const int w    = tid >> 6;
    const int lane = tid & 63;
    const int quad = lane >> 4;
    const int l16  = lane & 15;
    const int mh   = w & 1;
    const int nh   = w >> 1;

    __shared__ unsigned short As[128][32];
    __shared__ unsigned short Bs[128][32];

    f32x4 zero = {0.f, 0.f, 0.f, 0.f};
    f32x4 acc[4][4];
#pragma unroll
    for (int i = 0; i < 4; ++i)
#pragma unroll
        for (int j = 0; j < 4; ++j) acc[i][j] = zero;

    gemm_mainloop(cb, woT, As, Bs, acc, m0, n0, tid, mh, nh, l16, quad);

#pragma unroll
    for (int nt = 0; nt < 4; ++nt) {
        const int n = n0 + nh * 64 + nt * 16 + l16;
        const float bvv = bo[n];
#pragma unroll
        for (int mt = 0; mt < 4; ++mt) {
            const int mbase = m0 + mh * 64 + mt * 16 + quad * 4;
#pragma unroll
            for (int r = 0; r < 4; ++r)
                out[(size_t)(mbase + r) * DD + n] = acc[mt][nt][r] + bvv;
        }
    }
}

// ---------------------------------------------------------------------------
// MFMA flash attention, transposed-S formulation.
//   S^T = K·Q^T  (C layout: col=l16=query, row=key) -> per-lane softmax state
//   O^T = V^T·P^T (C layout: col=query, row=d)
// Double-buffered K/V staging, ONE barrier per K-tile.  LDS 45 KiB -> 3/CU.
// ---------------------------------------------------------------------------
__global__ __launch_bounds__(256, 3) void attn_mfma_kernel(
    const unsigned short* __restrict__ Qg, const unsigned short* __restrict__ Kg,
    const unsigned short* __restrict__ Vg, unsigned short* __restrict__ ctx)
{
    const int qt = (SS / 64 - 1) - blockIdx.x;   // big tiles first
    const int h  = blockIdx.y;
    const int b  = blockIdx.z;
    const int tid  = threadIdx.x;
    const int w    = tid >> 6;
    const int lane = tid & 63;
    const int quad = lane >> 4;
    const int l16  = lane & 15;
    const int q0   = qt * 64;

    const size_t bh = (size_t)(b * HH + h);
    const unsigned short* qp = Qg + bh * SS * HDD;
    const unsigned short* kp = Kg + bh * SS * HDD;
    const unsigned short* vp = Vg + bh * HDD * SS;   // [d][s]

    __shared__ unsigned short Ks[2][64][72];    // [buf][key][d]
    __shared__ unsigned short Vt[2][64][72];    // [buf][d][key]
    __shared__ unsigned short PsT[4][16][72];   // per-wave [query(l16)][key]

    // Q B-fragment in registers: B[k=d][n=query(l16)] = Q[query][d]
    const int query = q0 + w * 16 + l16;
    const bf16x8 qb0 = *(const bf16x8*)&qp[(size_t)query * HDD + quad * 8];
    const bf16x8 qb1 = *(const bf16x8*)&qp[(size_t)query * HDD + 32 + quad * 8];

    // staging pattern: 8 threads per 128B row
    const int pr = tid >> 3;           // 0..31 (p adds 32)
    const int po = (tid & 7) * 8;

    i32x4 kpre[2], vpre[2];
#pragma unroll
    for (int p = 0; p < 2; ++p) {      // tile 0 load
        int r = pr + p * 32;
        kpre[p] = *(const i32x4*)&kp[(size_t)r * HDD + po];
        vpre[p] = *(const i32x4*)&vp[(size_t)r * SS + po];
    }
#pragma unroll
    for (int p = 0; p < 2; ++p) {      // tile 0 -> buf 0
        int r = pr + p * 32;
        *(i32x4*)&Ks[0][r][po] = kpre[p];
        *(i32x4*)&Vt[0][r][po] = vpre[p];
    }
    if (qt >= 1) {                     // prefetch tile 1
#pragma unroll
        for (int p = 0; p < 2; ++p) {
            int r = pr + p * 32;
            kpre[p] = *(const i32x4*)&kp[(size_t)(64 + r) * HDD + po];
            vpre[p] = *(const i32x4*)&vp[(size_t)r * SS + 64 + po];
        }
    }

    f32x4 zero = {0.f, 0.f, 0.f, 0.f};
    f32x4 o_acc[4];
    float m_i = -INFINITY, l_i = 0.f;
#pragma unroll
    for (int i = 0; i < 4; ++i) o_acc[i] = zero;

    for (int kt = 0; kt <= qt; ++kt) {
        const int cbuf = kt & 1;
        const int k0   = kt * 64;
        __syncthreads();   // buf[cbuf] writes visible; prior reads of cbuf^1 done

        if (kt + 1 <= qt) {            // write next tile to back buffer
#pragma unroll
            for (int p = 0; p < 2; ++p) {
                int r = pr + p * 32;
                *(i32x4*)&Ks[cbuf ^ 1][r][po] = kpre[p];
                *(i32x4*)&Vt[cbuf ^ 1][r][po] = vpre[p];
            }
        }
        if (kt + 2 <= qt) {            // prefetch tile kt+2
            const int kn = (kt + 2) * 64;
#pragma unroll
            for (int p = 0; p < 2; ++p) {
                int r = pr + p * 32;
                kpre[p] = *(const i32x4*)&kp[(size_t)(kn + r) * HDD + po];
                vpre[p] = *(const i32x4*)&vp[(size_t)r * SS + kn + po];
            }
        }

        // ---- S^T = K·Q^T : 64 keys x 16 queries per wave ----
        f32x4 s_acc[4];
#pragma unroll
        for (int t = 0; t < 4; ++t) s_acc[t] = zero;
#pragma unroll
        for (int t = 0; t < 4; ++t) {
            bf16x8 klo = *(const bf16x8*)&Ks[cbuf][t * 16 + l16][quad * 8];
            bf16x8 khi = *(const bf16x8*)&Ks[cbuf][t * 16 + l16][32 + quad * 8];
            s_acc[t] = mfma16(klo, qb0, s_acc[t]);
            s_acc[t] = mfma16(khi, qb1, s_acc[t]);
        }

        // ---- per-lane online softmax (lane owns one query) ----
        float ps[4][4];
        float mx = -INFINITY;
#pragma unroll
        for (int t = 0; t < 4; ++t)
#pragma unroll
            for (int r = 0; r < 4; ++r) {
                const int key = k0 + t * 16 + quad * 4 + r;
                float val = s_acc[t][r] * 0.125f;
                if (kt == qt && key > query) val = -INFINITY;
                ps[t][r] = val;
                mx = fmaxf(mx, val);
            }
        mx = fmaxf(mx, __shfl_xor(mx, 16));
        mx = fmaxf(mx, __shfl_xor(mx, 32));
        const float mnew  = fmaxf(m_i, mx);
        const float alpha = __expf(m_i - mnew);
        float lsum = 0.f;
#pragma unroll
        for (int t = 0; t < 4; ++t)
#pragma unroll
            for (int r = 0; r < 4; ++r) {
                float pv = __expf(ps[t][r] - mnew);
                ps[t][r] = pv;
                lsum += pv;
            }
        lsum += __shfl_xor(lsum, 16);
        lsum += __shfl_xor(lsum, 32);
        l_i = l_i * alpha + lsum;
        m_i = mnew;
#pragma unroll
        for (int t = 0; t < 4; ++t)
#pragma unroll
            for (int r = 0; r < 4; ++r) o_acc[t][r] *= alpha;

        // ---- stage P^T (per-wave slab, packed 8B writes) ----
#pragma unroll
        for (int t = 0; t < 4; ++t) {
            ushort4 pk;
            pk.x = f2b(ps[t][0]);
            pk.y = f2b(ps[t][1]);
            pk.z = f2b(ps[t][2]);
            pk.w = f2b(ps[t][3]);
            *(ushort4*)&PsT[w][l16][t * 16 + quad * 4] = pk;
        }

        // ---- O^T += V^T · P^T ----
        bf16x8 pb0 = *(const bf16x8*)&PsT[w][l16][quad * 8];
        bf16x8 pb1 = *(const bf16x8*)&PsT[w][l16][32 + quad * 8];
#pragma unroll
        for (int t2 = 0; t2 < 4; ++t2) {
            bf16x8 vlo = *(const bf16x8*)&Vt[cbuf][t2 * 16 + l16][quad * 8];
            bf16x8 vhi = *(const bf16x8*)&Vt[cbuf][t2 * 16 + l16][32 + quad * 8];
            o_acc[t2] = mfma16(vlo, pb0, o_acc[t2]);
            o_acc[t2] = mfma16(vhi, pb1, o_acc[t2]);
        }
    }

    // ---- epilogue: normalize, bounce O^T -> [q][d] through PsT, store ----
    const float inv = 1.0f / l_i;
#pragma unroll
    for (int t2 = 0; t2 < 4; ++t2) {
        ushort4 pk;
        pk.x = f2b(o_acc[t2][0] * inv);
        pk.y = f2b(o_acc[t2][1] * inv);
        pk.z = f2b(o_acc[t2][2] * inv);
        pk.w = f2b(o_acc[t2][3] * inv);
        *(ushort4*)&PsT[w][l16][t2 * 16 + quad * 4] = pk;   // T[query][d]
    }
    __syncthreads();
    const unsigned short* Tf = (const unsigned short*)PsT;  // row stride 72
#pragma unroll
    for (int p2 = 0; p2 < 2; ++p2) {
        int c   = p2 * 256 + tid;
        int row = c >> 3;      // 0..63 = query offset
        int dc  = c & 7;
        *(i32x4*)&ctx[((size_t)(b * SS + q0 + row)) * DD + h * HDD + dc * 8] =
            *(const i32x4*)&Tf[row * 72 + dc * 8];
    }
}

// ---------------------------------------------------------------------------
extern "C" void kernel_launch(void* const* d_in, const int* in_sizes, int n_in,
                              void* d_out, int out_size, void* d_ws, size_t ws_size,
                              hipStream_t stream)
{
    const float* x  = (const float*)d_in[0];
    const float* wq = (const float*)d_in[1];
    const float* bq = (const float*)d_in[2];
    const float* wk = (const float*)d_in[3];
    const float* bk = (const float*)d_in[4];
    const float* wv = (const float*)d_in[5];
    const float* bv = (const float*)d_in[6];
    const float* wo = (const float*)d_in[7];
    const float* bo = (const float*)d_in[8];
    float* out = (float*)d_out;

    char* p = (char*)d_ws;
    const size_t XB = (size_t)BSR * DD * 2;
    const size_t WB = (size_t)DD * DD * 2;
    unsigned short* xb  = (unsigned short*)p;            p += XB;
    unsigned short* wqT = (unsigned short*)p;            p += WB;
    unsigned short* wkT = (unsigned short*)p;            p += WB;
    unsigned short* wvT = (unsigned short*)p;            p += WB;
    unsigned short* woT = (unsigned short*)p;            p += WB;
    unsigned short* Qg  = (unsigned short*)p;            p += XB;
    unsigned short* Kg  = (unsigned short*)p;            p += XB;
    unsigned short* Vg  = (unsigned short*)p;            p += XB;
    unsigned short* cb  = (unsigned short*)p;            p += XB;

    conv_x_kernel<<<BSR * DD / (256 * 8), 256, 0, stream>>>(x, xb);
    conv_wT_kernel<<<dim3(DD / 64, DD / 64, 4), 256, 0, stream>>>(
        wq, wk, wv, wo, wqT, wkT, wvT, woT);
    qkv_gemm_kernel<<<dim3(BSR / 128, DD / 128, 3), 256, 0, stream>>>(
        xb, wqT, wkT, wvT, bq, bk, bv, Qg, Kg, Vg);
    attn_mfma_kernel<<<dim3(SS / 64, HH, BB), 256, 0, stream>>>(Qg, Kg, Vg, cb);
    out_gemm_kernel<<<dim3(BSR / 128, DD / 128), 256, 0, stream>>>(cb, woT, bo, out);
}